// Round 5
// baseline (569.763 us; speedup 1.0000x reference)
//
#include <hip/hip_runtime.h>
#include <hip/hip_bf16.h>
#include <stdint.h>

#define HCH 256
#define GEO 13
#define DEPTH 3
#define EPSBN 1e-5f
#define MFMA __builtin_amdgcn_mfma_f32_16x16x32_bf16

typedef __attribute__((ext_vector_type(8))) short short8;
typedef __attribute__((ext_vector_type(4))) float floatx4;

typedef __attribute__((address_space(1))) const void g_void;
typedef __attribute__((address_space(3))) void l_void;

// fp32 -> bf16 RNE
__device__ __forceinline__ short f2bs(float f) {
    unsigned u = __float_as_uint(f);
    unsigned r = (u + 0x7fffu + ((u >> 16) & 1u)) >> 16;
    return (short)r;
}

// ---------------- k_prep: weights->bf16 (transposed), node/geo->bf16, BN fold,
//                  output zeroing, branch compaction (cnt zeroed by memset before)
__global__ void k_prep(const float* __restrict__ W0, const float* __restrict__ Wh,
                       const float* __restrict__ b0, const float* __restrict__ bh,
                       const float* __restrict__ gm, const float* __restrict__ bt,
                       const float* __restrict__ mn, const float* __restrict__ vr,
                       const float* __restrict__ att,
                       const float* __restrict__ node, const float* __restrict__ geo,
                       const int* __restrict__ edx_ij, const int* __restrict__ edx_jk,
                       const int* __restrict__ nei_p,
                       short* __restrict__ W0t, short* __restrict__ Wht,
                       float* __restrict__ sc, float* __restrict__ of,
                       short* __restrict__ node_bf, short* __restrict__ geo_bf,
                       int* __restrict__ lists, int* __restrict__ cnt,
                       float4* __restrict__ outz, int n4out,
                       int E, int d_in_dim, int nb_node, int nb_geo, int nb_out) {
    const int B_W0 = 100, B_WH = 96, B_SC = 16;
    __shared__ short s[32][256];
    int b = blockIdx.x, t = threadIdx.x;
    if (b < B_W0) {
        int c = b % 25, br = b / 25;
        #pragma unroll
        for (int kk = 0; kk < 32; ++kk) {
            int kidx = c * 32 + kk;
            float v = (kidx < d_in_dim) ? W0[((size_t)br * d_in_dim + kidx) * HCH + t] : 0.f;
            s[kk][t] = f2bs(v);   // coalesced global read (n fastest)
        }
        __syncthreads();
        size_t obase = ((size_t)(b) * 256 + t) * 32;
        #pragma unroll
        for (int g = 0; g < 4; ++g) {
            short8 v;
            #pragma unroll
            for (int j = 0; j < 8; ++j) v[j] = s[g * 8 + j][t];
            *reinterpret_cast<short8*>(W0t + obase + g * 8) = v;
        }
    } else if (b < B_W0 + B_WH) {
        int idx = b - B_W0;
        int c = idx & 7; idx >>= 3;
        int l = idx % 3, br = idx / 3;
        #pragma unroll
        for (int kk = 0; kk < 32; ++kk) {
            float v = Wh[((size_t)(br * DEPTH + l) * HCH + (c * 32 + kk)) * HCH + t];
            s[kk][t] = f2bs(v);
        }
        __syncthreads();
        size_t obase = ((size_t)(b - B_W0) * 256 + t) * 32;
        #pragma unroll
        for (int g = 0; g < 4; ++g) {
            short8 v;
            #pragma unroll
            for (int j = 0; j < 8; ++j) v[j] = s[g * 8 + j][t];
            *reinterpret_cast<short8*>(Wht + obase + g * 8) = v;
        }
    } else if (b < B_W0 + B_WH + B_SC) {
        int idx = (b - B_W0 - B_WH) * 256 + t; // 4096 elems
        int col = idx & 255, l = (idx >> 8) & 3, br = idx >> 10;
        int gi = (br * (DEPTH + 1) + l) * HCH + col;
        float sA = gm[gi] * rsqrtf(vr[gi] + EPSBN);
        float bias = (l == 0) ? b0[br * HCH + col] : bh[(br * DEPTH + (l - 1)) * HCH + col];
        float ofv = (bias - mn[gi]) * sA + bt[gi];
        if (l == 3) { float av = att[br]; sA *= av; ofv *= av; }  // fold att (relu out >=0)
        sc[idx] = sA;
        of[idx] = ofv;
    } else if (b < B_W0 + B_WH + B_SC + nb_node) {
        // node fp32 -> bf16, 8 elems/thread, coalesced
        size_t i = ((size_t)(b - B_W0 - B_WH - B_SC) * 256 + t) * 8;
        const float4* src = reinterpret_cast<const float4*>(node + i);
        float4 v0 = src[0], v1 = src[1];
        short8 pk;
        pk[0] = f2bs(v0.x); pk[1] = f2bs(v0.y); pk[2] = f2bs(v0.z); pk[3] = f2bs(v0.w);
        pk[4] = f2bs(v1.x); pk[5] = f2bs(v1.y); pk[6] = f2bs(v1.z); pk[7] = f2bs(v1.w);
        *reinterpret_cast<short8*>(node_bf + i) = pk;
    } else if (b < B_W0 + B_WH + B_SC + nb_node + nb_geo) {
        // geo [E][13] fp32 -> [E][32] bf16 zero-padded
        int i = (b - B_W0 - B_WH - B_SC - nb_node) * 256 + t;
        int e = i >> 2, cc = i & 3;
        if (e < E) {
            short8 pk;
            #pragma unroll
            for (int j = 0; j < 8; ++j) {
                int col = cc * 8 + j;
                pk[j] = (col < GEO) ? f2bs(geo[(size_t)e * GEO + col]) : (short)0;
            }
            *reinterpret_cast<short8*>(geo_bf + (size_t)e * 32 + cc * 8) = pk;
        }
    } else if (b < B_W0 + B_WH + B_SC + nb_node + nb_geo + nb_out) {
        // zero output
        int i = (b - (B_W0 + B_WH + B_SC + nb_node + nb_geo)) * 256 + t;
        if (i < n4out) outz[i] = make_float4(0.f, 0.f, 0.f, 0.f);
    } else {
        // wave-aggregated branch compaction (4 atomics per wave)
        int e = (b - (B_W0 + B_WH + B_SC + nb_node + nb_geo + nb_out)) * 256 + t;
        int NEI = nei_p[0];
        int lane = t & 63;
        int br = -1;
        if (e < E)
            br = ((edx_ij[e] < NEI) ? 0 : 2) + ((edx_jk[e] < NEI) ? 0 : 1);
        unsigned long long lt = (lane == 63) ? 0x7fffffffffffffffull
                                             : ((1ull << lane) - 1ull);
        #pragma unroll
        for (int bb = 0; bb < 4; ++bb) {
            unsigned long long mk = __ballot(br == bb);
            if (mk) {
                int leader = __ffsll((long long)mk) - 1;
                int base = 0;
                if (lane == leader) base = atomicAdd(&cnt[bb], (int)__popcll(mk));
                base = __shfl(base, leader);
                if (br == bb) {
                    int pos = base + (int)__popcll(mk & lt);
                    lists[(size_t)bb * E + pos] = e;
                }
            }
        }
    }
}

// ---------------- k_main v6: 64-edge tile, 256 threads / 4 waves, wave tile 64x64.
// Design point from v1..v5 data: keep v1's >=3 blocks/CU latency hiding (v5's
// 1-block/CU double-buffer was latency-bound at 337us despite halved traffic),
// while cutting LDS A-read amplification 8x -> 4x (128KB/phase vs v1's 256KB)
// at B-amplification 1x (each wave owns 64 unique cols; v4's B-doubling avoided).
// acc[4][4]=64 AGPRs; launch_bounds(256,3) -> 170-reg cap, est ~140 live, no spill.
// Gathers: global_load_lds + XOR-swizzle (v3/v5-verified), frees gather VGPRs.
// Stall between issue/drain barriers absorbed by 2 co-resident blocks; the
// independent geo chunk is placed inside part-1's issue->drain window as cover.
__global__ __launch_bounds__(256, 3)
void k_main(const short* __restrict__ node_bf, const short* __restrict__ geo_bf,
            const int* __restrict__ eidx,
            const short* __restrict__ W0t, const short* __restrict__ Wht,
            const float* __restrict__ sc, const float* __restrict__ of,
            const int* __restrict__ lists, const int* __restrict__ cnt,
            float* __restrict__ out, int E) {
    __shared__ __align__(16) short A[64][256];    // 32 KB, XOR-swizzled rows (512 B)
    __shared__ __align__(16) short Ageo[64][40];  // 5 KB, 80 B row stride
    __shared__ int s_idx[3][64];
    __shared__ int s_e[64];

    int c0 = cnt[0], c1 = cnt[1], c2 = cnt[2], c3 = cnt[3];
    int t0 = (c0 + 63) >> 6, t1 = (c1 + 63) >> 6, t2 = (c2 + 63) >> 6, t3 = (c3 + 63) >> 6;
    int b = blockIdx.x;
    int br, tile, count;
    if (b < t0)                     { br = 0; tile = b;                count = c0; }
    else if (b < t0 + t1)           { br = 1; tile = b - t0;           count = c1; }
    else if (b < t0 + t1 + t2)      { br = 2; tile = b - t0 - t1;      count = c2; }
    else if (b < t0 + t1 + t2 + t3) { br = 3; tile = b - t0 - t1 - t2; count = c3; }
    else return;
    int m = count - tile * 64; if (m > 64) m = 64;

    int t = threadIdx.x;
    if (t < 64) {
        int e = (t < m) ? lists[(size_t)br * E + (size_t)tile * 64 + t] : 0;
        s_e[t] = (t < m) ? e : -1;
        s_idx[0][t] = eidx[e];
        s_idx[1][t] = eidx[E + e];
        s_idx[2][t] = eidx[2 * E + e];
    }
    __syncthreads();   // indices visible

    int wvid = t >> 6, lane = t & 63, quad = lane >> 4, l16 = lane & 15;
    int swz = (l16 & 7) << 4;              // row&7 == l16&7 for all A-read rows

    floatx4 acc[4][4];
    #pragma unroll
    for (int rt = 0; rt < 4; ++rt)
        #pragma unroll
        for (int ct = 0; ct < 4; ++ct)
            #pragma unroll
            for (int r = 0; r < 4; ++r) acc[rt][ct][r] = 0.f;

    int boff[4];
    #pragma unroll
    for (int ct = 0; ct < 4; ++ct)
        boff[ct] = (wvid * 64 + ct * 16 + l16) * 32 + quad * 8;
    int aoff[4];
    #pragma unroll
    for (int rt = 0; rt < 4; ++rt)
        aoff[rt] = (rt * 16 + l16) * 512;   // byte offset of A row

    const char* Ab = (const char*)&A[0][0];
    char* Aw = (char*)&A[0][0];
    short* Ag = &Ageo[0][0];

    // --- stage one 64-row node part: wave wvid stages rows [wvid*16, wvid*16+16),
    // 2 rows per global_load_lds (1 KB). Global source pre-swizzled; LDS dest linear.
    auto stage_nodes = [&](const int* idxp) {
        #pragma unroll
        for (int i = 0; i < 8; ++i) {
            int r0 = (wvid * 8 + i) * 2;
            int row = r0 + (lane >> 5);
            int e = idxp[row];
            int soff = ((lane & 31) * 16) ^ ((row & 7) << 4);
            const char* src = (const char*)(node_bf + (size_t)e * HCH) + soff;
            __builtin_amdgcn_global_load_lds((g_void*)src, (l_void*)(&A[r0][0]), 16, 0, 0);
        }
    };

    // --- 8-chunk gemm (K=256): 4 A ds_read_b128 + 4 B b128 + 16 MFMA per chunk ---
    auto do_chunks8 = [&](const short* Wbase) {
        #pragma unroll
        for (int c = 0; c < 8; ++c) {
            short8 af[4];
            #pragma unroll
            for (int rt = 0; rt < 4; ++rt)
                af[rt] = *reinterpret_cast<const short8*>(
                    Ab + aoff[rt] + ((c * 64 + quad * 16) ^ swz));
            #pragma unroll
            for (int ct = 0; ct < 4; ++ct) {
                short8 bc = *reinterpret_cast<const short8*>(
                    Wbase + (size_t)c * 8192 + boff[ct]);
                #pragma unroll
                for (int rt = 0; rt < 4; ++rt)
                    acc[rt][ct] = MFMA(af[rt], bc, acc[rt][ct], 0, 0, 0);
            }
        }
    };

    // ---------------- layer 0: 3 node parts (i,j,k) + geo tail chunk ----------------
    {   // geo into its own buffer (plain stores; covered by the first barrier)
        int grow = t >> 2, gp = (t & 3) * 8;
        int ge = s_e[grow];
        short8 gv;
        if (ge >= 0) gv = *reinterpret_cast<const short8*>(geo_bf + (size_t)ge * 32 + gp);
        else {
            #pragma unroll
            for (int j = 0; j < 8; ++j) gv[j] = 0;
        }
        *reinterpret_cast<short8*>(Ag + grow * 40 + gp) = gv;
    }
    stage_nodes(s_idx[0]);
    __syncthreads();                 // part0 + geo published (vmcnt drained)

    do_chunks8(W0t + (size_t)(br * 25 + 0) * 8192);
    __syncthreads();                 // A reads of part0 done
    stage_nodes(s_idx[1]);
    // geo chunk (K 768..799) — independent of A, covers part1's gather latency
    {
        short8 afg[4];
        #pragma unroll
        for (int rt = 0; rt < 4; ++rt)
            afg[rt] = *reinterpret_cast<const short8*>(
                Ag + (rt * 16 + l16) * 40 + quad * 8);
        const short* Wg = W0t + (size_t)(br * 25 + 24) * 8192;
        #pragma unroll
        for (int ct = 0; ct < 4; ++ct) {
            short8 bc = *reinterpret_cast<const short8*>(Wg + boff[ct]);
            #pragma unroll
            for (int rt = 0; rt < 4; ++rt)
                acc[rt][ct] = MFMA(afg[rt], bc, acc[rt][ct], 0, 0, 0);
        }
    }
    __syncthreads();                 // part1 published

    do_chunks8(W0t + (size_t)(br * 25 + 8) * 8192);
    __syncthreads();                 // A reads of part1 done
    stage_nodes(s_idx[2]);
    __syncthreads();                 // part2 published

    do_chunks8(W0t + (size_t)(br * 25 + 16) * 8192);

    // ---------------- BN+relu epilogues, hidden layers, final scatter ----------------
    for (int l = 0; l < 4; ++l) {
        float sv[4], ov[4];
        #pragma unroll
        for (int ct = 0; ct < 4; ++ct) {
            int col = wvid * 64 + ct * 16 + l16;
            sv[ct] = sc[(br * 4 + l) * HCH + col];
            ov[ct] = of[(br * 4 + l) * HCH + col];
        }
        if (l < 3) {
            __syncthreads();  // matmul's A reads done before overwrite
            #pragma unroll
            for (int rt = 0; rt < 4; ++rt)
                #pragma unroll
                for (int ct = 0; ct < 4; ++ct) {
                    int colb = (wvid * 64 + ct * 16 + l16) * 2;
                    #pragma unroll
                    for (int r = 0; r < 4; ++r) {
                        int row = rt * 16 + quad * 4 + r;
                        float h = fmaxf(acc[rt][ct][r] * sv[ct] + ov[ct], 0.f);
                        *reinterpret_cast<short*>(
                            Aw + row * 512 + (colb ^ ((row & 7) << 4))) = f2bs(h);
                        acc[rt][ct][r] = 0.f;
                    }
                }
            __syncthreads();
            do_chunks8(Wht + (size_t)((br * 3 + l) * 8) * 8192);
        } else {
            // final: relu (leaky+att folded into sc/of) -> scatter-add on node i
            #pragma unroll
            for (int rt = 0; rt < 4; ++rt)
                #pragma unroll
                for (int r = 0; r < 4; ++r) {
                    int row = rt * 16 + quad * 4 + r;
                    if (row < m) {
                        float* orow = out + (size_t)s_idx[0][row] * HCH + wvid * 64 + l16;
                        #pragma unroll
                        for (int ct = 0; ct < 4; ++ct) {
                            float h = fmaxf(acc[rt][ct][r] * sv[ct] + ov[ct], 0.f);
                            atomicAdd(orow + ct * 16, h);
                        }
                    }
                }
        }
    }
}

// ---------------- host launcher ----------------
extern "C" void kernel_launch(void* const* d_in, const int* in_sizes, int n_in,
                              void* d_out, int out_size, void* d_ws, size_t ws_size,
                              hipStream_t stream) {
    const float* node  = (const float*)d_in[0];
    const float* geo   = (const float*)d_in[1];
    const int*   eidx  = (const int*)d_in[2];
    const int*   edxij = (const int*)d_in[3];
    const int*   edxjk = (const int*)d_in[4];
    const float* att   = (const float*)d_in[5];
    const float* W0    = (const float*)d_in[6];
    const float* b0    = (const float*)d_in[7];
    const float* Wh    = (const float*)d_in[8];
    const float* bh    = (const float*)d_in[9];
    const float* gm    = (const float*)d_in[10];
    const float* bt    = (const float*)d_in[11];
    const float* mn    = (const float*)d_in[12];
    const float* vr    = (const float*)d_in[13];
    const int*   neip  = (const int*)d_in[14];

    int E = in_sizes[3];
    int N = in_sizes[0] / HCH;
    int d_in_dim = in_sizes[6] / (4 * HCH);   // 781

    uint8_t* w = (uint8_t*)d_ws;
    size_t off = 0;
    short* W0t  = (short*)(w + off); off += (size_t)4 * 25 * 256 * 32 * 2;
    short* Wht  = (short*)(w + off); off += (size_t)4 * 3 * 8 * 256 * 32 * 2;
    float* sc   = (float*)(w + off); off += 4096 * 4;
    float* of   = (float*)(w + off); off += 4096 * 4;
    int*   lists= (int*)(w + off);   off += (size_t)4 * E * 4;
    int*   cnt  = (int*)(w + off);   off += 16;
    short* node_bf = (short*)(w + off); off += (size_t)N * HCH * 2;
    short* geo_bf  = (short*)(w + off); off += (size_t)E * 32 * 2;

    float* out = (float*)d_out;
    int n4 = out_size / 4;                    // out floats -> float4 count

    hipMemsetAsync(cnt, 0, 16, stream);       // branch counters

    int nb_node = N / 8;                      // N*256 elems / (256 thr * 8)
    int nb_geo  = (4 * E + 255) / 256;
    int nb_out  = (n4 + 255) / 256;
    int nb_cmp  = (E + 255) / 256;
    k_prep<<<100 + 96 + 16 + nb_node + nb_geo + nb_out + nb_cmp, 256, 0, stream>>>(
        W0, Wh, b0, bh, gm, bt, mn, vr, att, node, geo, edxij, edxjk, neip,
        W0t, Wht, sc, of, node_bf, geo_bf, lists, cnt,
        (float4*)out, n4, E, d_in_dim, nb_node, nb_geo, nb_out);

    int T = (E >> 6) + 8;
    k_main<<<T, 256, 0, stream>>>(node_bf, geo_bf, eidx, W0t, Wht,
                                  sc, of, lists, cnt, out, E);
}

// Round 6
// 409.402 us; speedup vs baseline: 1.3917x; 1.3917x over previous
//
#include <hip/hip_runtime.h>
#include <hip/hip_bf16.h>
#include <stdint.h>

#define HCH 256
#define GEO 13
#define DEPTH 3
#define EPSBN 1e-5f
#define MFMA __builtin_amdgcn_mfma_f32_16x16x32_bf16

typedef __attribute__((ext_vector_type(8))) short short8;
typedef __attribute__((ext_vector_type(4))) float floatx4;

// fp32 -> bf16 RNE
__device__ __forceinline__ short f2bs(float f) {
    unsigned u = __float_as_uint(f);
    unsigned r = (u + 0x7fffu + ((u >> 16) & 1u)) >> 16;
    return (short)r;
}

// ---------------- k_prep: weights->bf16 (transposed), node/geo->bf16, BN fold,
//                  output zeroing, branch compaction (cnt zeroed by memset before)
__global__ void k_prep(const float* __restrict__ W0, const float* __restrict__ Wh,
                       const float* __restrict__ b0, const float* __restrict__ bh,
                       const float* __restrict__ gm, const float* __restrict__ bt,
                       const float* __restrict__ mn, const float* __restrict__ vr,
                       const float* __restrict__ att,
                       const float* __restrict__ node, const float* __restrict__ geo,
                       const int* __restrict__ edx_ij, const int* __restrict__ edx_jk,
                       const int* __restrict__ nei_p,
                       short* __restrict__ W0t, short* __restrict__ Wht,
                       float* __restrict__ sc, float* __restrict__ of,
                       short* __restrict__ node_bf, short* __restrict__ geo_bf,
                       int* __restrict__ lists, int* __restrict__ cnt,
                       float4* __restrict__ outz, int n4out,
                       int E, int d_in_dim, int nb_node, int nb_geo, int nb_out) {
    const int B_W0 = 100, B_WH = 96, B_SC = 16;
    __shared__ short s[32][256];
    int b = blockIdx.x, t = threadIdx.x;
    if (b < B_W0) {
        int c = b % 25, br = b / 25;
        #pragma unroll
        for (int kk = 0; kk < 32; ++kk) {
            int kidx = c * 32 + kk;
            float v = (kidx < d_in_dim) ? W0[((size_t)br * d_in_dim + kidx) * HCH + t] : 0.f;
            s[kk][t] = f2bs(v);   // coalesced global read (n fastest)
        }
        __syncthreads();
        size_t obase = ((size_t)(b) * 256 + t) * 32;
        #pragma unroll
        for (int g = 0; g < 4; ++g) {
            short8 v;
            #pragma unroll
            for (int j = 0; j < 8; ++j) v[j] = s[g * 8 + j][t];
            *reinterpret_cast<short8*>(W0t + obase + g * 8) = v;
        }
    } else if (b < B_W0 + B_WH) {
        int idx = b - B_W0;
        int c = idx & 7; idx >>= 3;
        int l = idx % 3, br = idx / 3;
        #pragma unroll
        for (int kk = 0; kk < 32; ++kk) {
            float v = Wh[((size_t)(br * DEPTH + l) * HCH + (c * 32 + kk)) * HCH + t];
            s[kk][t] = f2bs(v);
        }
        __syncthreads();
        size_t obase = ((size_t)(b - B_W0) * 256 + t) * 32;
        #pragma unroll
        for (int g = 0; g < 4; ++g) {
            short8 v;
            #pragma unroll
            for (int j = 0; j < 8; ++j) v[j] = s[g * 8 + j][t];
            *reinterpret_cast<short8*>(Wht + obase + g * 8) = v;
        }
    } else if (b < B_W0 + B_WH + B_SC) {
        int idx = (b - B_W0 - B_WH) * 256 + t; // 4096 elems
        int col = idx & 255, l = (idx >> 8) & 3, br = idx >> 10;
        int gi = (br * (DEPTH + 1) + l) * HCH + col;
        float sA = gm[gi] * rsqrtf(vr[gi] + EPSBN);
        float bias = (l == 0) ? b0[br * HCH + col] : bh[(br * DEPTH + (l - 1)) * HCH + col];
        float ofv = (bias - mn[gi]) * sA + bt[gi];
        if (l == 3) { float av = att[br]; sA *= av; ofv *= av; }  // fold att (relu out >=0)
        sc[idx] = sA;
        of[idx] = ofv;
    } else if (b < B_W0 + B_WH + B_SC + nb_node) {
        // node fp32 -> bf16, 8 elems/thread, coalesced
        size_t i = ((size_t)(b - B_W0 - B_WH - B_SC) * 256 + t) * 8;
        const float4* src = reinterpret_cast<const float4*>(node + i);
        float4 v0 = src[0], v1 = src[1];
        short8 pk;
        pk[0] = f2bs(v0.x); pk[1] = f2bs(v0.y); pk[2] = f2bs(v0.z); pk[3] = f2bs(v0.w);
        pk[4] = f2bs(v1.x); pk[5] = f2bs(v1.y); pk[6] = f2bs(v1.z); pk[7] = f2bs(v1.w);
        *reinterpret_cast<short8*>(node_bf + i) = pk;
    } else if (b < B_W0 + B_WH + B_SC + nb_node + nb_geo) {
        // geo [E][13] fp32 -> [E][32] bf16 zero-padded
        int i = (b - B_W0 - B_WH - B_SC - nb_node) * 256 + t;
        int e = i >> 2, cc = i & 3;
        if (e < E) {
            short8 pk;
            #pragma unroll
            for (int j = 0; j < 8; ++j) {
                int col = cc * 8 + j;
                pk[j] = (col < GEO) ? f2bs(geo[(size_t)e * GEO + col]) : (short)0;
            }
            *reinterpret_cast<short8*>(geo_bf + (size_t)e * 32 + cc * 8) = pk;
        }
    } else if (b < B_W0 + B_WH + B_SC + nb_node + nb_geo + nb_out) {
        // zero output
        int i = (b - (B_W0 + B_WH + B_SC + nb_node + nb_geo)) * 256 + t;
        if (i < n4out) outz[i] = make_float4(0.f, 0.f, 0.f, 0.f);
    } else {
        // wave-aggregated branch compaction (4 atomics per wave)
        int e = (b - (B_W0 + B_WH + B_SC + nb_node + nb_geo + nb_out)) * 256 + t;
        int NEI = nei_p[0];
        int lane = t & 63;
        int br = -1;
        if (e < E)
            br = ((edx_ij[e] < NEI) ? 0 : 2) + ((edx_jk[e] < NEI) ? 0 : 1);
        unsigned long long lt = (lane == 63) ? 0x7fffffffffffffffull
                                             : ((1ull << lane) - 1ull);
        #pragma unroll
        for (int bb = 0; bb < 4; ++bb) {
            unsigned long long mk = __ballot(br == bb);
            if (mk) {
                int leader = __ffsll((long long)mk) - 1;
                int base = 0;
                if (lane == leader) base = atomicAdd(&cnt[bb], (int)__popcll(mk));
                base = __shfl(base, leader);
                if (br == bb) {
                    int pos = base + (int)__popcll(mk & lt);
                    lists[(size_t)bb * E + pos] = e;
                }
            }
        }
    }
}

// ---------------- k_main v7: v1's exact geometry (64-edge tile, 8 waves 1x8 of
// 64x32, acc[4][2], reg ping-pong gathers) -- the measured optimum of v1..v6 --
// plus four micro-levers aimed at the measured latency-convoy profile (all pipes
// <40% busy, per-pipe times ADD to the 181us wall):
//  1. B-ring prefetch distance 2 -> 3 (L2 B-load latency ~250cy vs ~60cy/chunk
//     of covering work; depth-3 covers ~180cy).
//  2. A pad -> XOR swizzle (byte ^= (row&7)<<4): A-reads exact 2-way (free,
//     m136); pad had ~29% residual conflict overhead. Formulas v3/v6-verified.
//  3. s_setprio(1) around MFMA clusters (T5; 3 independent blocks/CU = role
//     diversity for the CU scheduler).
//  4. Geo chunk merged into part-2 phase via its own buffer (v6-verified):
//     15 -> 13 barriers.
__global__ __launch_bounds__(512)
void k_main(const short* __restrict__ node_bf, const short* __restrict__ geo_bf,
            const int* __restrict__ eidx,
            const short* __restrict__ W0t, const short* __restrict__ Wht,
            const float* __restrict__ sc, const float* __restrict__ of,
            const int* __restrict__ lists, const int* __restrict__ cnt,
            float* __restrict__ out, int E) {
    __shared__ __align__(16) short A[64][256];    // 32 KB, XOR-swizzled rows (512 B)
    __shared__ __align__(16) short Ageo[64][40];  // 5 KB, 80 B row stride
    __shared__ int s_idx[3][64];
    __shared__ int s_e[64];

    int c0 = cnt[0], c1 = cnt[1], c2 = cnt[2], c3 = cnt[3];
    int t0 = (c0 + 63) >> 6, t1 = (c1 + 63) >> 6, t2 = (c2 + 63) >> 6, t3 = (c3 + 63) >> 6;
    int b = blockIdx.x;
    int br, tile, count;
    if (b < t0)                     { br = 0; tile = b;                count = c0; }
    else if (b < t0 + t1)           { br = 1; tile = b - t0;           count = c1; }
    else if (b < t0 + t1 + t2)      { br = 2; tile = b - t0 - t1;      count = c2; }
    else if (b < t0 + t1 + t2 + t3) { br = 3; tile = b - t0 - t1 - t2; count = c3; }
    else return;
    int m = count - tile * 64; if (m > 64) m = 64;

    int t = threadIdx.x;
    if (t < 64) {
        int e = (t < m) ? lists[(size_t)br * E + (size_t)tile * 64 + t] : 0;
        s_e[t] = (t < m) ? e : -1;
        s_idx[0][t] = eidx[e];
        s_idx[1][t] = eidx[E + e];
        s_idx[2][t] = eidx[2 * E + e];
    }
    __syncthreads();   // indices visible

    int wv = t >> 6, lane = t & 63, quad = lane >> 4, l16 = lane & 15;
    int rbase = t >> 5, cc8 = (t & 31) * 8;   // staging coords: rows it*16+rbase, 16B piece
    int swz = (l16 & 7) << 4;                 // A-read swizzle (row&7 == l16&7)

    floatx4 acc[4][2];
    #pragma unroll
    for (int rt = 0; rt < 4; ++rt)
        #pragma unroll
        for (int ct = 0; ct < 2; ++ct)
            #pragma unroll
            for (int r = 0; r < 4; ++r) acc[rt][ct][r] = 0.f;

    int boff[2];
    #pragma unroll
    for (int ct = 0; ct < 2; ++ct)
        boff[ct] = (wv * 32 + ct * 16 + l16) * 32 + quad * 8;

    const char* Ab = (const char*)&A[0][0];
    char* Aw = (char*)&A[0][0];
    short* Ag = &Ageo[0][0];

    // 8-chunk gemm with 4-slot B prefetch ring, distance 3 (fully unrolled)
    auto do_chunks8 = [&](const short* Wbase) {
        short8 bb[4][2];
        #pragma unroll
        for (int s = 0; s < 3; ++s)
            #pragma unroll
            for (int ct = 0; ct < 2; ++ct)
                bb[s][ct] = *reinterpret_cast<const short8*>(
                    Wbase + (size_t)s * 8192 + boff[ct]);
        #pragma unroll
        for (int c = 0; c < 8; ++c) {
            if (c + 3 < 8) {
                const short* Bn = Wbase + (size_t)(c + 3) * 8192;
                #pragma unroll
                for (int ct = 0; ct < 2; ++ct)
                    bb[(c + 3) & 3][ct] = *reinterpret_cast<const short8*>(Bn + boff[ct]);
            }
            short8 af[4];
            #pragma unroll
            for (int rt = 0; rt < 4; ++rt)
                af[rt] = *reinterpret_cast<const short8*>(
                    Ab + (rt * 16 + l16) * 512 + ((c * 64 + quad * 16) ^ swz));
            __builtin_amdgcn_s_setprio(1);
            #pragma unroll
            for (int rt = 0; rt < 4; ++rt)
                #pragma unroll
                for (int ct = 0; ct < 2; ++ct)
                    acc[rt][ct] = MFMA(af[rt], bb[c & 3][ct], acc[rt][ct], 0, 0, 0);
            __builtin_amdgcn_s_setprio(0);
        }
    };
    // single geo chunk (reads Ageo)
    auto do_chunk1 = [&](const short* Wbase) {
        short8 bc[2];
        #pragma unroll
        for (int ct = 0; ct < 2; ++ct)
            bc[ct] = *reinterpret_cast<const short8*>(Wbase + boff[ct]);
        short8 af[4];
        #pragma unroll
        for (int rt = 0; rt < 4; ++rt)
            af[rt] = *reinterpret_cast<const short8*>(
                Ag + (rt * 16 + l16) * 40 + quad * 8);
        __builtin_amdgcn_s_setprio(1);
        #pragma unroll
        for (int rt = 0; rt < 4; ++rt)
            #pragma unroll
            for (int ct = 0; ct < 2; ++ct)
                acc[rt][ct] = MFMA(af[rt], bc[ct], acc[rt][ct], 0, 0, 0);
        __builtin_amdgcn_s_setprio(0);
    };

    // ---------------- layer 0: gathers pre-issued one part ahead ----------------
    // geo staged up front into its own buffer; published by part-0's barrier,
    // consumed after part-2's chunks with no extra barrier (buffer never reused).
    if (t < 256) {
        int grow = t >> 2, gp = (t & 3) * 8;
        int ge = s_e[grow];
        short8 gv;
        if (ge >= 0) gv = *reinterpret_cast<const short8*>(geo_bf + (size_t)ge * 32 + gp);
        else {
            #pragma unroll
            for (int j = 0; j < 8; ++j) gv[j] = 0;
        }
        *reinterpret_cast<short8*>(Ag + grow * 40 + gp) = gv;
    }
    short8 g[2][4];    // ping-pong gather regs (part p in g[p&1])
    #pragma unroll
    for (int it = 0; it < 4; ++it)
        g[0][it] = *reinterpret_cast<const short8*>(
            node_bf + (size_t)s_idx[0][it * 16 + rbase] * HCH + cc8);

    #pragma unroll
    for (int p = 0; p < 3; ++p) {
        __syncthreads();               // WAR: part p-1's A reads done (p=0: cheap)
        #pragma unroll
        for (int it = 0; it < 4; ++it) {
            int row = it * 16 + rbase;
            *reinterpret_cast<short8*>(
                Aw + row * 512 + ((cc8 * 2) ^ ((row & 7) << 4))) = g[p & 1][it];
        }
        __syncthreads();               // publish part p (p=0 also publishes Ageo)
        // issue next part's gathers (completes behind this part's 8-chunk compute)
        if (p < 2) {
            const int* idxs = s_idx[p + 1];
            #pragma unroll
            for (int it = 0; it < 4; ++it)
                g[(p + 1) & 1][it] = *reinterpret_cast<const short8*>(
                    node_bf + (size_t)idxs[it * 16 + rbase] * HCH + cc8);
        }
        do_chunks8(W0t + (size_t)(br * 25 + p * 8) * 8192);
    }
    do_chunk1(W0t + (size_t)(br * 25 + 24) * 8192);   // geo chunk, barrier-free

    // ---------------- BN+relu epilogues, hidden layers, final scatter ----------------
    for (int l = 0; l < 4; ++l) {
        float sv[2], ov[2];
        #pragma unroll
        for (int ct = 0; ct < 2; ++ct) {
            int col = wv * 32 + ct * 16 + l16;
            sv[ct] = sc[(br * 4 + l) * HCH + col];
            ov[ct] = of[(br * 4 + l) * HCH + col];
        }
        if (l < 3) {
            __syncthreads();  // matmul's A reads done before overwrite
            #pragma unroll
            for (int rt = 0; rt < 4; ++rt)
                #pragma unroll
                for (int ct = 0; ct < 2; ++ct) {
                    int colb = (wv * 32 + ct * 16 + l16) * 2;
                    #pragma unroll
                    for (int r = 0; r < 4; ++r) {
                        int row = rt * 16 + quad * 4 + r;
                        float h = fmaxf(acc[rt][ct][r] * sv[ct] + ov[ct], 0.f);
                        *reinterpret_cast<short*>(
                            Aw + row * 512 + (colb ^ ((row & 7) << 4))) = f2bs(h);
                        acc[rt][ct][r] = 0.f;
                    }
                }
            __syncthreads();
            do_chunks8(Wht + (size_t)((br * 3 + l) * 8) * 8192);
        } else {
            // final: relu (leaky+att folded into sc/of) -> scatter-add on node i
            #pragma unroll
            for (int rt = 0; rt < 4; ++rt)
                #pragma unroll
                for (int r = 0; r < 4; ++r) {
                    int row = rt * 16 + quad * 4 + r;
                    if (row < m) {
                        float* orow = out + (size_t)s_idx[0][row] * HCH + wv * 32 + l16;
                        #pragma unroll
                        for (int ct = 0; ct < 2; ++ct) {
                            float h = fmaxf(acc[rt][ct][r] * sv[ct] + ov[ct], 0.f);
                            atomicAdd(orow + ct * 16, h);
                        }
                    }
                }
        }
    }
}

// ---------------- host launcher ----------------
extern "C" void kernel_launch(void* const* d_in, const int* in_sizes, int n_in,
                              void* d_out, int out_size, void* d_ws, size_t ws_size,
                              hipStream_t stream) {
    const float* node  = (const float*)d_in[0];
    const float* geo   = (const float*)d_in[1];
    const int*   eidx  = (const int*)d_in[2];
    const int*   edxij = (const int*)d_in[3];
    const int*   edxjk = (const int*)d_in[4];
    const float* att   = (const float*)d_in[5];
    const float* W0    = (const float*)d_in[6];
    const float* b0    = (const float*)d_in[7];
    const float* Wh    = (const float*)d_in[8];
    const float* bh    = (const float*)d_in[9];
    const float* gm    = (const float*)d_in[10];
    const float* bt    = (const float*)d_in[11];
    const float* mn    = (const float*)d_in[12];
    const float* vr    = (const float*)d_in[13];
    const int*   neip  = (const int*)d_in[14];

    int E = in_sizes[3];
    int N = in_sizes[0] / HCH;
    int d_in_dim = in_sizes[6] / (4 * HCH);   // 781

    uint8_t* w = (uint8_t*)d_ws;
    size_t off = 0;
    short* W0t  = (short*)(w + off); off += (size_t)4 * 25 * 256 * 32 * 2;
    short* Wht  = (short*)(w + off); off += (size_t)4 * 3 * 8 * 256 * 32 * 2;
    float* sc   = (float*)(w + off); off += 4096 * 4;
    float* of   = (float*)(w + off); off += 4096 * 4;
    int*   lists= (int*)(w + off);   off += (size_t)4 * E * 4;
    int*   cnt  = (int*)(w + off);   off += 16;
    short* node_bf = (short*)(w + off); off += (size_t)N * HCH * 2;
    short* geo_bf  = (short*)(w + off); off += (size_t)E * 32 * 2;

    float* out = (float*)d_out;
    int n4 = out_size / 4;                    // out floats -> float4 count

    hipMemsetAsync(cnt, 0, 16, stream);       // branch counters

    int nb_node = N / 8;                      // N*256 elems / (256 thr * 8)
    int nb_geo  = (4 * E + 255) / 256;
    int nb_out  = (n4 + 255) / 256;
    int nb_cmp  = (E + 255) / 256;
    k_prep<<<100 + 96 + 16 + nb_node + nb_geo + nb_out + nb_cmp, 256, 0, stream>>>(
        W0, Wh, b0, bh, gm, bt, mn, vr, att, node, geo, edxij, edxjk, neip,
        W0t, Wht, sc, of, node_bf, geo_bf, lists, cnt,
        (float4*)out, n4, E, d_in_dim, nb_node, nb_geo, nb_out);

    int T = (E >> 6) + 8;
    k_main<<<T, 512, 0, stream>>>(node_bf, geo_bf, eidx, W0t, Wht,
                                  sc, of, lists, cnt, out, E);
}

// Round 7
// 393.672 us; speedup vs baseline: 1.4473x; 1.0400x over previous
//
#include <hip/hip_runtime.h>
#include <hip/hip_bf16.h>
#include <stdint.h>

#define HCH 256
#define GEO 13
#define DEPTH 3
#define EPSBN 1e-5f
#define MFMA __builtin_amdgcn_mfma_f32_16x16x32_bf16

typedef __attribute__((ext_vector_type(8))) short short8;
typedef __attribute__((ext_vector_type(4))) float floatx4;

// fp32 -> bf16 RNE
__device__ __forceinline__ short f2bs(float f) {
    unsigned u = __float_as_uint(f);
    unsigned r = (u + 0x7fffu + ((u >> 16) & 1u)) >> 16;
    return (short)r;
}

// ---------------- k_prep: weights->bf16 (transposed), node/geo->bf16, BN fold,
//                  output zeroing, branch compaction (cnt zeroed by memset before)
__global__ void k_prep(const float* __restrict__ W0, const float* __restrict__ Wh,
                       const float* __restrict__ b0, const float* __restrict__ bh,
                       const float* __restrict__ gm, const float* __restrict__ bt,
                       const float* __restrict__ mn, const float* __restrict__ vr,
                       const float* __restrict__ att,
                       const float* __restrict__ node, const float* __restrict__ geo,
                       const int* __restrict__ edx_ij, const int* __restrict__ edx_jk,
                       const int* __restrict__ nei_p,
                       short* __restrict__ W0t, short* __restrict__ Wht,
                       float* __restrict__ sc, float* __restrict__ of,
                       short* __restrict__ node_bf, short* __restrict__ geo_bf,
                       int* __restrict__ lists, int* __restrict__ cnt,
                       float4* __restrict__ outz, int n4out,
                       int E, int d_in_dim, int nb_node, int nb_geo, int nb_out) {
    const int B_W0 = 100, B_WH = 96, B_SC = 16;
    __shared__ short s[32][256];
    int b = blockIdx.x, t = threadIdx.x;
    if (b < B_W0) {
        int c = b % 25, br = b / 25;
        #pragma unroll
        for (int kk = 0; kk < 32; ++kk) {
            int kidx = c * 32 + kk;
            float v = (kidx < d_in_dim) ? W0[((size_t)br * d_in_dim + kidx) * HCH + t] : 0.f;
            s[kk][t] = f2bs(v);   // coalesced global read (n fastest)
        }
        __syncthreads();
        size_t obase = ((size_t)(b) * 256 + t) * 32;
        #pragma unroll
        for (int g = 0; g < 4; ++g) {
            short8 v;
            #pragma unroll
            for (int j = 0; j < 8; ++j) v[j] = s[g * 8 + j][t];
            *reinterpret_cast<short8*>(W0t + obase + g * 8) = v;
        }
    } else if (b < B_W0 + B_WH) {
        int idx = b - B_W0;
        int c = idx & 7; idx >>= 3;
        int l = idx % 3, br = idx / 3;
        #pragma unroll
        for (int kk = 0; kk < 32; ++kk) {
            float v = Wh[((size_t)(br * DEPTH + l) * HCH + (c * 32 + kk)) * HCH + t];
            s[kk][t] = f2bs(v);
        }
        __syncthreads();
        size_t obase = ((size_t)(b - B_W0) * 256 + t) * 32;
        #pragma unroll
        for (int g = 0; g < 4; ++g) {
            short8 v;
            #pragma unroll
            for (int j = 0; j < 8; ++j) v[j] = s[g * 8 + j][t];
            *reinterpret_cast<short8*>(Wht + obase + g * 8) = v;
        }
    } else if (b < B_W0 + B_WH + B_SC) {
        int idx = (b - B_W0 - B_WH) * 256 + t; // 4096 elems
        int col = idx & 255, l = (idx >> 8) & 3, br = idx >> 10;
        int gi = (br * (DEPTH + 1) + l) * HCH + col;
        float sA = gm[gi] * rsqrtf(vr[gi] + EPSBN);
        float bias = (l == 0) ? b0[br * HCH + col] : bh[(br * DEPTH + (l - 1)) * HCH + col];
        float ofv = (bias - mn[gi]) * sA + bt[gi];
        if (l == 3) { float av = att[br]; sA *= av; ofv *= av; }  // fold att (relu out >=0)
        sc[idx] = sA;
        of[idx] = ofv;
    } else if (b < B_W0 + B_WH + B_SC + nb_node) {
        // node fp32 -> bf16, 8 elems/thread, coalesced
        size_t i = ((size_t)(b - B_W0 - B_WH - B_SC) * 256 + t) * 8;
        const float4* src = reinterpret_cast<const float4*>(node + i);
        float4 v0 = src[0], v1 = src[1];
        short8 pk;
        pk[0] = f2bs(v0.x); pk[1] = f2bs(v0.y); pk[2] = f2bs(v0.z); pk[3] = f2bs(v0.w);
        pk[4] = f2bs(v1.x); pk[5] = f2bs(v1.y); pk[6] = f2bs(v1.z); pk[7] = f2bs(v1.w);
        *reinterpret_cast<short8*>(node_bf + i) = pk;
    } else if (b < B_W0 + B_WH + B_SC + nb_node + nb_geo) {
        // geo [E][13] fp32 -> [E][32] bf16 zero-padded
        int i = (b - B_W0 - B_WH - B_SC - nb_node) * 256 + t;
        int e = i >> 2, cc = i & 3;
        if (e < E) {
            short8 pk;
            #pragma unroll
            for (int j = 0; j < 8; ++j) {
                int col = cc * 8 + j;
                pk[j] = (col < GEO) ? f2bs(geo[(size_t)e * GEO + col]) : (short)0;
            }
            *reinterpret_cast<short8*>(geo_bf + (size_t)e * 32 + cc * 8) = pk;
        }
    } else if (b < B_W0 + B_WH + B_SC + nb_node + nb_geo + nb_out) {
        // zero output
        int i = (b - (B_W0 + B_WH + B_SC + nb_node + nb_geo)) * 256 + t;
        if (i < n4out) outz[i] = make_float4(0.f, 0.f, 0.f, 0.f);
    } else {
        // wave-aggregated branch compaction (4 atomics per wave)
        int e = (b - (B_W0 + B_WH + B_SC + nb_node + nb_geo + nb_out)) * 256 + t;
        int NEI = nei_p[0];
        int lane = t & 63;
        int br = -1;
        if (e < E)
            br = ((edx_ij[e] < NEI) ? 0 : 2) + ((edx_jk[e] < NEI) ? 0 : 1);
        unsigned long long lt = (lane == 63) ? 0x7fffffffffffffffull
                                             : ((1ull << lane) - 1ull);
        #pragma unroll
        for (int bb = 0; bb < 4; ++bb) {
            unsigned long long mk = __ballot(br == bb);
            if (mk) {
                int leader = __ffsll((long long)mk) - 1;
                int base = 0;
                if (lane == leader) base = atomicAdd(&cnt[bb], (int)__popcll(mk));
                base = __shfl(base, leader);
                if (br == bb) {
                    int pos = base + (int)__popcll(mk & lt);
                    lists[(size_t)bb * E + pos] = e;
                }
            }
        }
    }
}

// ---------------- k_main v8: v1 VERBATIM core (the measured optimum: 64-edge tile,
// 8 waves 1x8 of 64x32, acc[4][2], padded A[64][264], bb[3][2] reg B-ring,
// pipelined reg ping-pong gathers, NO setprio/swizzle) + two REGISTER-NEUTRAL levers:
//  1. Geo-merge (v7-verified): geo in its own 5KB buffer, consumed as a tail chunk
//     after part 2 -> one fewer staging round, 15 -> 13 barriers.
//  2. XCD-chunked bijective block swizzle (m204): blocks are branch-contiguous;
//     chunking gives each XCD ~196 consecutive blocks ~= one branch -> its 784KB
//     weight set stays L2-resident instead of all-4-branches (3.1MB) thrash.
// Reg budget rule learned from v2/v5/v6/v7: unified file, acc AGPRs count;
// 3 blocks/CU requires VGPR_Count <= ~53. v1 measured 44; these levers add ~0.
__global__ __launch_bounds__(512)
void k_main(const short* __restrict__ node_bf, const short* __restrict__ geo_bf,
            const int* __restrict__ eidx,
            const short* __restrict__ W0t, const short* __restrict__ Wht,
            const float* __restrict__ sc, const float* __restrict__ of,
            const int* __restrict__ lists, const int* __restrict__ cnt,
            float* __restrict__ out, int E) {
    __shared__ __align__(16) short A[64][264];    // 33.8 KB, +8 pad (v1 layout)
    __shared__ __align__(16) short Ageo[64][40];  // 5 KB, 80 B row stride
    __shared__ int s_idx[3][64];
    __shared__ int s_e[64];

    // XCD-chunked bijective swizzle (m204): xcd = bid%8 processes a contiguous
    // chunk of the branch-ordered tile space -> per-XCD L2 weight locality.
    int nwg = gridDim.x;
    int q = nwg >> 3, r = nwg & 7;
    int xcd = blockIdx.x & 7, jj = blockIdx.x >> 3;
    int b = ((xcd < r) ? xcd * (q + 1) : r * (q + 1) + (xcd - r) * q) + jj;

    int c0 = cnt[0], c1 = cnt[1], c2 = cnt[2], c3 = cnt[3];
    int t0 = (c0 + 63) >> 6, t1 = (c1 + 63) >> 6, t2 = (c2 + 63) >> 6, t3 = (c3 + 63) >> 6;
    int br, tile, count;
    if (b < t0)                     { br = 0; tile = b;                count = c0; }
    else if (b < t0 + t1)           { br = 1; tile = b - t0;           count = c1; }
    else if (b < t0 + t1 + t2)      { br = 2; tile = b - t0 - t1;      count = c2; }
    else if (b < t0 + t1 + t2 + t3) { br = 3; tile = b - t0 - t1 - t2; count = c3; }
    else return;
    int m = count - tile * 64; if (m > 64) m = 64;

    int t = threadIdx.x;
    if (t < 64) {
        int e = (t < m) ? lists[(size_t)br * E + (size_t)tile * 64 + t] : 0;
        s_e[t] = (t < m) ? e : -1;
        s_idx[0][t] = eidx[e];
        s_idx[1][t] = eidx[E + e];
        s_idx[2][t] = eidx[2 * E + e];
    }
    __syncthreads();   // indices visible

    int wv = t >> 6, lane = t & 63, quad = lane >> 4, l16 = lane & 15;
    int rbase = t >> 5, cc8 = (t & 31) * 8;   // staging coords: rows it*16+rbase, 16B piece

    floatx4 acc[4][2];
    #pragma unroll
    for (int rt = 0; rt < 4; ++rt)
        #pragma unroll
        for (int ct = 0; ct < 2; ++ct)
            #pragma unroll
            for (int r2 = 0; r2 < 4; ++r2) acc[rt][ct][r2] = 0.f;

    int boff[2];
    #pragma unroll
    for (int ct = 0; ct < 2; ++ct)
        boff[ct] = (wv * 32 + ct * 16 + l16) * 32 + quad * 8;

    short* Ag = &Ageo[0][0];

    // 8-chunk gemm with v1's 3-slot B prefetch ring (refill before consume, dist 2)
    auto do_chunks8 = [&](const short* Wbase) {
        short8 bb[3][2];
        #pragma unroll
        for (int ct = 0; ct < 2; ++ct) {
            bb[0][ct] = *reinterpret_cast<const short8*>(Wbase + boff[ct]);
            bb[1][ct] = *reinterpret_cast<const short8*>(Wbase + 8192 + boff[ct]);
        }
        #pragma unroll
        for (int c = 0; c < 8; ++c) {
            if (c + 2 < 8) {
                const short* Bn = Wbase + (size_t)(c + 2) * 8192;
                #pragma unroll
                for (int ct = 0; ct < 2; ++ct)
                    bb[(c + 2) % 3][ct] = *reinterpret_cast<const short8*>(Bn + boff[ct]);
            }
            short8 af[4];
            #pragma unroll
            for (int rt = 0; rt < 4; ++rt)
                af[rt] = *reinterpret_cast<const short8*>(&A[rt * 16 + l16][c * 32 + quad * 8]);
            #pragma unroll
            for (int rt = 0; rt < 4; ++rt)
                #pragma unroll
                for (int ct = 0; ct < 2; ++ct)
                    acc[rt][ct] = MFMA(af[rt], bb[c % 3][ct], acc[rt][ct], 0, 0, 0);
        }
    };
    // single geo chunk (reads Ageo; published since part-0's barrier, never reused)
    auto do_chunk1 = [&](const short* Wbase) {
        short8 bc[2];
        #pragma unroll
        for (int ct = 0; ct < 2; ++ct)
            bc[ct] = *reinterpret_cast<const short8*>(Wbase + boff[ct]);
        short8 af[4];
        #pragma unroll
        for (int rt = 0; rt < 4; ++rt)
            af[rt] = *reinterpret_cast<const short8*>(Ag + (rt * 16 + l16) * 40 + quad * 8);
        #pragma unroll
        for (int rt = 0; rt < 4; ++rt)
            #pragma unroll
            for (int ct = 0; ct < 2; ++ct)
                acc[rt][ct] = MFMA(af[rt], bc[ct], acc[rt][ct], 0, 0, 0);
    };

    // ---------------- layer 0: gathers pre-issued one part ahead (v1 pattern) -------
    // geo staged up front into its own buffer (plain stores; covered by part-0's
    // publish barrier; consumed after part-2's chunks with no extra barrier).
    if (t < 256) {
        int grow = t >> 2, gp = (t & 3) * 8;
        int ge = s_e[grow];
        short8 gv;
        if (ge >= 0) gv = *reinterpret_cast<const short8*>(geo_bf + (size_t)ge * 32 + gp);
        else {
            #pragma unroll
            for (int j = 0; j < 8; ++j) gv[j] = 0;
        }
        *reinterpret_cast<short8*>(Ag + grow * 40 + gp) = gv;
    }
    short8 g[2][4];    // ping-pong gather regs (part p in g[p&1])
    #pragma unroll
    for (int it = 0; it < 4; ++it)
        g[0][it] = *reinterpret_cast<const short8*>(
            node_bf + (size_t)s_idx[0][it * 16 + rbase] * HCH + cc8);

    #pragma unroll
    for (int p = 0; p < 3; ++p) {
        __syncthreads();               // WAR: part p-1's A reads done (p=0: cheap)
        #pragma unroll
        for (int it = 0; it < 4; ++it)
            *reinterpret_cast<short8*>(&A[it * 16 + rbase][cc8]) = g[p & 1][it];
        __syncthreads();               // publish part p (p=0 also publishes Ageo)
        // issue next part's gathers (completes behind this part's 8-chunk compute)
        if (p < 2) {
            const int* idxs = s_idx[p + 1];
            #pragma unroll
            for (int it = 0; it < 4; ++it)
                g[(p + 1) & 1][it] = *reinterpret_cast<const short8*>(
                    node_bf + (size_t)idxs[it * 16 + rbase] * HCH + cc8);
        }
        do_chunks8(W0t + (size_t)(br * 25 + p * 8) * 8192);
    }
    do_chunk1(W0t + (size_t)(br * 25 + 24) * 8192);   // geo chunk, barrier-free

    // ---------------- BN+relu epilogues, hidden layers, final scatter ----------------
    for (int l = 0; l < 4; ++l) {
        float sv[2], ov[2];
        #pragma unroll
        for (int ct = 0; ct < 2; ++ct) {
            int col = wv * 32 + ct * 16 + l16;
            sv[ct] = sc[(br * 4 + l) * HCH + col];
            ov[ct] = of[(br * 4 + l) * HCH + col];
        }
        if (l < 3) {
            __syncthreads();  // matmul's A reads done before overwrite
            #pragma unroll
            for (int rt = 0; rt < 4; ++rt)
                #pragma unroll
                for (int ct = 0; ct < 2; ++ct) {
                    int col = wv * 32 + ct * 16 + l16;
                    #pragma unroll
                    for (int r2 = 0; r2 < 4; ++r2) {
                        int row = rt * 16 + quad * 4 + r2;
                        float h = fmaxf(acc[rt][ct][r2] * sv[ct] + ov[ct], 0.f);
                        A[row][col] = f2bs(h);
                        acc[rt][ct][r2] = 0.f;
                    }
                }
            __syncthreads();
            do_chunks8(Wht + (size_t)((br * 3 + l) * 8) * 8192);
        } else {
            // final: relu (leaky+att folded into sc/of) -> scatter-add on node i
            #pragma unroll
            for (int rt = 0; rt < 4; ++rt)
                #pragma unroll
                for (int r2 = 0; r2 < 4; ++r2) {
                    int row = rt * 16 + quad * 4 + r2;
                    if (row < m) {
                        float* orow = out + (size_t)s_idx[0][row] * HCH + wv * 32 + l16;
                        #pragma unroll
                        for (int ct = 0; ct < 2; ++ct) {
                            float h = fmaxf(acc[rt][ct][r2] * sv[ct] + ov[ct], 0.f);
                            atomicAdd(orow + ct * 16, h);
                        }
                    }
                }
        }
    }
}

// ---------------- host launcher ----------------
extern "C" void kernel_launch(void* const* d_in, const int* in_sizes, int n_in,
                              void* d_out, int out_size, void* d_ws, size_t ws_size,
                              hipStream_t stream) {
    const float* node  = (const float*)d_in[0];
    const float* geo   = (const float*)d_in[1];
    const int*   eidx  = (const int*)d_in[2];
    const int*   edxij = (const int*)d_in[3];
    const int*   edxjk = (const int*)d_in[4];
    const float* att   = (const float*)d_in[5];
    const float* W0    = (const float*)d_in[6];
    const float* b0    = (const float*)d_in[7];
    const float* Wh    = (const float*)d_in[8];
    const float* bh    = (const float*)d_in[9];
    const float* gm    = (const float*)d_in[10];
    const float* bt    = (const float*)d_in[11];
    const float* mn    = (const float*)d_in[12];
    const float* vr    = (const float*)d_in[13];
    const int*   neip  = (const int*)d_in[14];

    int E = in_sizes[3];
    int N = in_sizes[0] / HCH;
    int d_in_dim = in_sizes[6] / (4 * HCH);   // 781

    uint8_t* w = (uint8_t*)d_ws;
    size_t off = 0;
    short* W0t  = (short*)(w + off); off += (size_t)4 * 25 * 256 * 32 * 2;
    short* Wht  = (short*)(w + off); off += (size_t)4 * 3 * 8 * 256 * 32 * 2;
    float* sc   = (float*)(w + off); off += 4096 * 4;
    float* of   = (float*)(w + off); off += 4096 * 4;
    int*   lists= (int*)(w + off);   off += (size_t)4 * E * 4;
    int*   cnt  = (int*)(w + off);   off += 16;
    short* node_bf = (short*)(w + off); off += (size_t)N * HCH * 2;
    short* geo_bf  = (short*)(w + off); off += (size_t)E * 32 * 2;

    float* out = (float*)d_out;
    int n4 = out_size / 4;                    // out floats -> float4 count

    hipMemsetAsync(cnt, 0, 16, stream);       // branch counters

    int nb_node = N / 8;                      // N*256 elems / (256 thr * 8)
    int nb_geo  = (4 * E + 255) / 256;
    int nb_out  = (n4 + 255) / 256;
    int nb_cmp  = (E + 255) / 256;
    k_prep<<<100 + 96 + 16 + nb_node + nb_geo + nb_out + nb_cmp, 256, 0, stream>>>(
        W0, Wh, b0, bh, gm, bt, mn, vr, att, node, geo, edxij, edxjk, neip,
        W0t, Wht, sc, of, node_bf, geo_bf, lists, cnt,
        (float4*)out, n4, E, d_in_dim, nb_node, nb_geo, nb_out);

    int T = (E >> 6) + 8;
    k_main<<<T, 512, 0, stream>>>(node_bf, geo_bf, eidx, W0t, Wht,
                                  sc, of, lists, cnt, out, E);
}